// Round 2
// baseline (41.197 us; speedup 1.0000x reference)
//
#include <hip/hip_runtime.h>

#define HEAD_DIM   128
#define HIDDEN     2048
#define MAX_SEQ    2048
#define NUM_HEADS  16
#define NUM_KV     8
#define LAYER_IDX  5
#define NSPLIT     64
#define CHUNK      (MAX_SEQ / NSPLIT)   // 32
#define SCALE      0.08838834764831845f // 1/sqrt(128)

// ws layout (floats)
#define WS_Q     0        // 2048 (pre-scaled by SCALE)
#define WS_K     2048     // 1024
#define WS_V     3072     // 1024
#define WS_M     4096     // 16*64
#define WS_L     5120     // 16*64
#define WS_O     6144     // 16*64*128
#define WS_ATTN  137216   // 2048
#define WS_CNT   139264   // 8 uints

__device__ __forceinline__ float wave_reduce_sum(float v) {
    #pragma unroll
    for (int off = 32; off > 0; off >>= 1) v += __shfl_xor(v, off);
    return v;
}
__device__ __forceinline__ float group32_reduce_sum(float v) {
    #pragma unroll
    for (int off = 16; off > 0; off >>= 1) v += __shfl_xor(v, off);
    return v;
}
__device__ __forceinline__ float group32_reduce_max(float v) {
    #pragma unroll
    for (int off = 16; off > 0; off >>= 1) v = fmaxf(v, __shfl_xor(v, off));
    return v;
}

// ---------------- Kernel 1: q/k/v projections, 8 rows per block ----------------
__global__ __launch_bounds__(256) void qkv_kernel(const float* __restrict__ x,
                                                  const float* __restrict__ q_w,
                                                  const float* __restrict__ k_w,
                                                  const float* __restrict__ v_w,
                                                  float* __restrict__ ws,
                                                  unsigned int* __restrict__ cnt) {
    const int t = threadIdx.x;
    if (blockIdx.x == 0 && t < NUM_KV) cnt[t] = 0u;   // re-zero combine counters each call

    float4 x0 = ((const float4*)x)[t];
    float4 x1 = ((const float4*)x)[t + 256];
    const int row0 = blockIdx.x * 8;

    float p[8];
    #pragma unroll
    for (int r = 0; r < 8; ++r) {
        const int row = row0 + r;
        const float* w;
        if (row < 2048)      w = q_w + (size_t)row * HIDDEN;
        else if (row < 3072) w = k_w + (size_t)(row - 2048) * HIDDEN;
        else                 w = v_w + (size_t)(row - 3072) * HIDDEN;
        float4 a0 = ((const float4*)w)[t];
        float4 a1 = ((const float4*)w)[t + 256];
        p[r] = a0.x * x0.x + a0.y * x0.y + a0.z * x0.z + a0.w * x0.w
             + a1.x * x1.x + a1.y * x1.y + a1.z * x1.z + a1.w * x1.w;
    }
    #pragma unroll
    for (int r = 0; r < 8; ++r) p[r] = wave_reduce_sum(p[r]);

    __shared__ float red[8][4];
    const int wave = t >> 6, lane = t & 63;
    if (lane == 0) {
        #pragma unroll
        for (int r = 0; r < 8; ++r) red[r][wave] = p[r];
    }
    __syncthreads();
    if (t < 8) {
        const int row = row0 + t;
        float v = red[t][0] + red[t][1] + red[t][2] + red[t][3];
        if (row < 2048)      ws[WS_Q + row] = v * SCALE;
        else if (row < 3072) ws[WS_K + (row - 2048)] = v;
        else                 ws[WS_V + (row - 3072)] = v;
    }
}

// ------- Kernel 2: flash-decode partials + in-kernel combine (last block per g) -------
__global__ __launch_bounds__(256) void attn_kernel(const float* __restrict__ kv_cache,
                                                   const float* __restrict__ wsq,
                                                   const int* __restrict__ cur_pos,
                                                   float* __restrict__ m_part,
                                                   float* __restrict__ l_part,
                                                   float* __restrict__ o_part,
                                                   float* __restrict__ attn,
                                                   unsigned int* __restrict__ cnt) {
    const int g     = blockIdx.x;      // kv head
    const int split = blockIdx.y;      // 0..NSPLIT-1
    const int s0    = split * CHUNK;
    const int cpos  = *cur_pos;
    const int t     = threadIdx.x;
    const int wave  = t >> 6, lane = t & 63;

    const float* kbase = kv_cache + ((size_t)(2 * LAYER_IDX)     * NUM_KV + g) * (size_t)MAX_SEQ * HEAD_DIM;
    const float* vbase = kv_cache + ((size_t)(2 * LAYER_IDX + 1) * NUM_KV + g) * (size_t)MAX_SEQ * HEAD_DIM;
    const float* knew  = wsq + WS_K + g * HEAD_DIM;
    const float* vnew  = wsq + WS_V + g * HEAD_DIM;
    const float* q0    = wsq + WS_Q + (g * 2 + 0) * HEAD_DIM;   // pre-scaled
    const float* q1    = wsq + WS_Q + (g * 2 + 1) * HEAD_DIM;

    __shared__ float  sc[2][CHUNK];
    __shared__ float  ee[2][CHUNK];
    __shared__ float  ml[2][2];
    __shared__ float4 smv[2][8][32];   // also reused as [4][64] reduce scratch in combine
    __shared__ float  wsc[2][NSPLIT];
    __shared__ float  linv[2];
    __shared__ int    lastf;

    // ---- scores: wave w covers positions w*8..w*8+7, lanes split d (float2) ----
    float2 q0v = *(const float2*)(q0 + lane * 2);
    float2 q1v = *(const float2*)(q1 + lane * 2);
    #pragma unroll
    for (int i = 0; i < CHUNK / 4; ++i) {
        const int j = wave * (CHUNK / 4) + i;
        const int s = s0 + j;
        const float* krow = (s == cpos) ? knew : (kbase + (size_t)s * HEAD_DIM);
        float2 kk = *(const float2*)(krow + lane * 2);
        float d0 = q0v.x * kk.x + q0v.y * kk.y;
        float d1 = q1v.x * kk.x + q1v.y * kk.y;
        d0 = wave_reduce_sum(d0);
        d1 = wave_reduce_sum(d1);
        if (lane == 0) { sc[0][j] = d0; sc[1][j] = d1; }
    }
    __syncthreads();

    // ---- wave-parallel softmax partial (2 reps x 32 vals in wave 0) ----
    if (t < 64) {
        const int rr = t >> 5, j = t & 31;
        float v = sc[rr][j];
        float m = group32_reduce_max(v);
        float e = __expf(v - m);
        ee[rr][j] = e;
        float l = group32_reduce_sum(e);
        if (j == 0) { ml[rr][0] = m; ml[rr][1] = l; }
    }
    __syncthreads();

    // ---- V accumulation: wave w, lanes -> (row_sub, q4); one load feeds both reps ----
    {
        const int rs = lane >> 5, q4 = lane & 31;
        float4 a0 = {0.f, 0.f, 0.f, 0.f}, a1 = {0.f, 0.f, 0.f, 0.f};
        #pragma unroll
        for (int pass = 0; pass < 4; ++pass) {
            const int j = pass * 8 + wave * 2 + rs;
            const int s = s0 + j;
            const float* vrow = (s == cpos) ? vnew : (vbase + (size_t)s * HEAD_DIM);
            float4 vv = ((const float4*)vrow)[q4];
            const float e0 = ee[0][j], e1 = ee[1][j];
            a0.x += e0 * vv.x; a0.y += e0 * vv.y; a0.z += e0 * vv.z; a0.w += e0 * vv.w;
            a1.x += e1 * vv.x; a1.y += e1 * vv.y; a1.z += e1 * vv.z; a1.w += e1 * vv.w;
        }
        smv[0][wave * 2 + rs][q4] = a0;
        smv[1][wave * 2 + rs][q4] = a1;
    }
    __syncthreads();
    if (t < 64) {
        const int rep = t >> 5, q4 = t & 31;
        float4 s = smv[rep][0][q4];
        #pragma unroll
        for (int r = 1; r < 8; ++r) {
            float4 b = smv[rep][r][q4];
            s.x += b.x; s.y += b.y; s.z += b.z; s.w += b.w;
        }
        const int h = g * 2 + rep;
        ((float4*)(o_part + ((size_t)h * NSPLIT + split) * HEAD_DIM))[q4] = s;
        if (q4 == 0) {
            m_part[h * NSPLIT + split] = ml[rep][0];
            l_part[h * NSPLIT + split] = ml[rep][1];
        }
    }
    __syncthreads();

    // ---- stream-K fixup: last block for this g combines both heads ----
    if (t == 0) {
        __threadfence();                                   // release our partials
        unsigned int old = atomicAdd(&cnt[g], 1u);
        lastf = (old == NSPLIT - 1);
    }
    __syncthreads();
    if (!lastf) return;
    __threadfence();                                       // acquire others' partials

    if (t < 128) {  // wave 0 -> head 2g, wave 1 -> head 2g+1
        const int hh = t >> 6, i = t & 63;
        const int h = g * 2 + hh;
        float m = m_part[h * NSPLIT + i];
        float M = m;
        #pragma unroll
        for (int off = 32; off > 0; off >>= 1) M = fmaxf(M, __shfl_xor(M, off));
        float w = __expf(m - M);
        wsc[hh][i] = w;
        float l = wave_reduce_sum(l_part[h * NSPLIT + i] * w);
        if (i == 0) linv[hh] = 1.0f / l;
    }
    __syncthreads();
    {
        const int hh = lane >> 5, q4 = lane & 31;  // wave covers 2 heads x 32 float4
        const int st = wave;                       // stripe of i (16 each)
        const int h = g * 2 + hh;
        const float4* ob = (const float4*)(o_part + (size_t)h * NSPLIT * HEAD_DIM);
        float4 acc = {0.f, 0.f, 0.f, 0.f};
        #pragma unroll
        for (int ii = 0; ii < 16; ++ii) {
            const int i = st * 16 + ii;
            const float w = wsc[hh][i];
            float4 ov = ob[i * 32 + q4];
            acc.x += w * ov.x; acc.y += w * ov.y; acc.z += w * ov.z; acc.w += w * ov.w;
        }
        float4* lred = (float4*)smv;               // [4][64]
        lred[st * 64 + lane] = acc;
    }
    __syncthreads();
    if (t < 64) {
        float4 s = ((float4*)smv)[lane];
        #pragma unroll
        for (int st = 1; st < 4; ++st) {
            float4 b = ((float4*)smv)[st * 64 + lane];
            s.x += b.x; s.y += b.y; s.z += b.z; s.w += b.w;
        }
        const float li = linv[lane >> 5];
        s.x *= li; s.y *= li; s.z *= li; s.w *= li;
        ((float4*)(attn + (size_t)(g * 2 + (lane >> 5)) * HEAD_DIM))[lane & 31] = s;
    }
}

// ---------------- Kernel 3: output projection, 4 rows per block ----------------
__global__ __launch_bounds__(256) void out_kernel(const float* __restrict__ o_w,
                                                  const float* __restrict__ attn,
                                                  float* __restrict__ out) {
    const int t = threadIdx.x;
    float4 x0 = ((const float4*)attn)[t];
    float4 x1 = ((const float4*)attn)[t + 256];
    const int row0 = blockIdx.x * 4;

    float p[4];
    #pragma unroll
    for (int r = 0; r < 4; ++r) {
        const float* w = o_w + (size_t)(row0 + r) * HIDDEN;
        float4 a0 = ((const float4*)w)[t];
        float4 a1 = ((const float4*)w)[t + 256];
        p[r] = a0.x * x0.x + a0.y * x0.y + a0.z * x0.z + a0.w * x0.w
             + a1.x * x1.x + a1.y * x1.y + a1.z * x1.z + a1.w * x1.w;
    }
    #pragma unroll
    for (int r = 0; r < 4; ++r) p[r] = wave_reduce_sum(p[r]);

    __shared__ float red[4][4];
    const int wave = t >> 6, lane = t & 63;
    if (lane == 0) {
        #pragma unroll
        for (int r = 0; r < 4; ++r) red[r][wave] = p[r];
    }
    __syncthreads();
    if (t < 4) out[row0 + t] = red[t][0] + red[t][1] + red[t][2] + red[t][3];
}

extern "C" void kernel_launch(void* const* d_in, const int* in_sizes, int n_in,
                              void* d_out, int out_size, void* d_ws, size_t ws_size,
                              hipStream_t stream) {
    const float* x    = (const float*)d_in[0];
    const float* kv   = (const float*)d_in[1];
    const float* q_w  = (const float*)d_in[2];
    const float* k_w  = (const float*)d_in[3];
    const float* v_w  = (const float*)d_in[4];
    const float* o_w  = (const float*)d_in[5];
    const int*   cpos = (const int*)d_in[6];
    float* ws  = (float*)d_ws;
    float* out = (float*)d_out;
    unsigned int* cnt = (unsigned int*)(ws + WS_CNT);

    qkv_kernel<<<512, 256, 0, stream>>>(x, q_w, k_w, v_w, ws, cnt);
    attn_kernel<<<dim3(NUM_KV, NSPLIT), 256, 0, stream>>>(
        kv, ws, cpos, ws + WS_M, ws + WS_L, ws + WS_O, ws + WS_ATTN, cnt);
    out_kernel<<<512, 256, 0, stream>>>(o_w, ws + WS_ATTN, out);
}